// Round 14
// baseline (59.747 us; speedup 1.0000x reference)
//
#include <hip/hip_runtime.h>

#define NCLS 30000
#define SLOT 64   // per-row edge-slot stride; P(deg>64) ~ 1e-24 for Poisson(16)

__device__ __forceinline__ unsigned short f2bf(float x) {
    unsigned int u = __float_as_uint(x);
    unsigned int r = (u + 0x7fffu + ((u >> 16) & 1u)) >> 16;   // RNE
    return (unsigned short)r;
}

// ---- transpose logits [M][N] -> flatTb [N][M] bf16; also zeroes cnt[n] ----
__global__ void transpose_in_kernel(const float* __restrict__ src,
                                    unsigned short* __restrict__ dst,
                                    int* __restrict__ cnt, int n, int m) {
    __shared__ float tile[32][33];
    int n0 = blockIdx.x * 32;
    int m0 = blockIdx.y * 32;
    int tx = threadIdx.x, ty = threadIdx.y;   // 32 x 8 threads
    if (blockIdx.y == 0) {
        int t = blockIdx.x * 256 + ty * 32 + tx;
        if (t < n) cnt[t] = 0;
    }
#pragma unroll
    for (int k = 0; k < 4; ++k) {
        int mm = m0 + ty + k * 8;
        int nn = n0 + tx;
        if (nn < n) tile[ty + k * 8][tx] = src[(size_t)mm * n + nn];
    }
    __syncthreads();
#pragma unroll
    for (int k = 0; k < 4; ++k) {
        int nn = n0 + ty + k * 8;
        int mm = m0 + tx;
        if (nn < n) dst[(size_t)nn * m + mm] = f2bf(tile[tx][ty + k * 8]);
    }
}

// ---- direct slotted scatter, 4 edges/thread (int4 loads) ----
__global__ void scatter_direct_kernel(const int* __restrict__ rows,
                                      const int* __restrict__ cols,
                                      const float* __restrict__ vals,
                                      int* __restrict__ cnt,
                                      uint2* __restrict__ epair, int nnz) {
    int e = (blockIdx.x * blockDim.x + threadIdx.x) * 4;
    if (e + 3 < nnz) {
        int4  r4 = *(const int4*)(rows + e);
        int4  c4 = *(const int4*)(cols + e);
        float4 v4 = *(const float4*)(vals + e);
        int p0 = atomicAdd(&cnt[r4.x], 1) & (SLOT - 1);
        epair[(size_t)r4.x * SLOT + p0] = make_uint2((unsigned)c4.x, __float_as_uint(v4.x));
        int p1 = atomicAdd(&cnt[r4.y], 1) & (SLOT - 1);
        epair[(size_t)r4.y * SLOT + p1] = make_uint2((unsigned)c4.y, __float_as_uint(v4.y));
        int p2 = atomicAdd(&cnt[r4.z], 1) & (SLOT - 1);
        epair[(size_t)r4.z * SLOT + p2] = make_uint2((unsigned)c4.z, __float_as_uint(v4.z));
        int p3 = atomicAdd(&cnt[r4.w], 1) & (SLOT - 1);
        epair[(size_t)r4.w * SLOT + p3] = make_uint2((unsigned)c4.w, __float_as_uint(v4.w));
    } else {
        for (int k = e; k < nnz; ++k) {
            int r = rows[k];
            int pos = atomicAdd(&cnt[r], 1) & (SLOT - 1);
            epair[(size_t)r * SLOT + pos] =
                make_uint2((unsigned)cols[k], __float_as_uint(vals[k]));
        }
    }
}

// ---- fused SpMM + renormalize + transpose-out + residual ----
// block = 512 threads (8 waves); block owns 32 rows; wave w does rows w*4..w*4+3
// processed as 2 PAIRS (a,b interleaved for 2x memory-level parallelism).
// Lane split: g = lane>>4 (edge sub-slot), sl = lane&15 (m = sl*8..sl*8+7);
// per chunk each lane gathers 16 B (uint4) -> one wave op covers 4 rows.
__global__ void __launch_bounds__(512)
spmm_fused_kernel(const int* __restrict__ cnt,
                  const uint2* __restrict__ epair,
                  const unsigned short* __restrict__ flatTb,
                  const float* __restrict__ logits,
                  float* __restrict__ out, int n) {
    __shared__ float tile[128][33];
    const int tid  = threadIdx.x;
    const int wave = tid >> 6;     // 0..7
    const int lane = tid & 63;
    const int g    = lane >> 4;    // edge slot within chunk: 0..3
    const int sl   = lane & 15;    // column slice: m = sl*8 .. sl*8+7
    const int r0   = blockIdx.x * 32;

    for (int kp = 0; kp < 2; ++kp) {
        int rl_a = wave * 4 + kp * 2;
        int r_a  = r0 + rl_a;
        if (r_a >= n) break;
        int r_b  = r_a + 1;
        bool has_b = (r_b < n);

        int len_a = __builtin_amdgcn_readfirstlane(cnt[r_a]);
        if (len_a > SLOT) len_a = SLOT;
        int len_b = 0;
        if (has_b) {
            len_b = __builtin_amdgcn_readfirstlane(cnt[r_b]);
            if (len_b > SLOT) len_b = SLOT;
        }
        int base_a = r_a * SLOT;
        int base_b = r_b * SLOT;

        float2 A0 = {0.f, 0.f}, A1 = {0.f, 0.f}, A2 = {0.f, 0.f}, A3 = {0.f, 0.f};
        float2 B0 = {0.f, 0.f}, B1 = {0.f, 0.f}, B2 = {0.f, 0.f}, B3 = {0.f, 0.f};
        float rsa = 0.f, rsb = 0.f;

        int maxlen = len_a > len_b ? len_a : len_b;
        for (int off = 0; off < maxlen; off += 4) {
            if (off < len_a) {                     // wave-uniform predicate
                uint2 ed = epair[base_a + off + g];
                bool act = (off + g) < len_a;
                unsigned c = act ? ed.x : 0u;
                float    v = act ? __uint_as_float(ed.y) : 0.f;
                uint4 x = *((const uint4*)(flatTb + (size_t)c * 128) + sl);
                A0.x += v * __uint_as_float(x.x << 16);
                A0.y += v * __uint_as_float(x.x & 0xffff0000u);
                A1.x += v * __uint_as_float(x.y << 16);
                A1.y += v * __uint_as_float(x.y & 0xffff0000u);
                A2.x += v * __uint_as_float(x.z << 16);
                A2.y += v * __uint_as_float(x.z & 0xffff0000u);
                A3.x += v * __uint_as_float(x.w << 16);
                A3.y += v * __uint_as_float(x.w & 0xffff0000u);
                rsa += v;
            }
            if (off < len_b) {
                uint2 ed = epair[base_b + off + g];
                bool act = (off + g) < len_b;
                unsigned c = act ? ed.x : 0u;
                float    v = act ? __uint_as_float(ed.y) : 0.f;
                uint4 x = *((const uint4*)(flatTb + (size_t)c * 128) + sl);
                B0.x += v * __uint_as_float(x.x << 16);
                B0.y += v * __uint_as_float(x.x & 0xffff0000u);
                B1.x += v * __uint_as_float(x.y << 16);
                B1.y += v * __uint_as_float(x.y & 0xffff0000u);
                B2.x += v * __uint_as_float(x.z << 16);
                B2.y += v * __uint_as_float(x.z & 0xffff0000u);
                B3.x += v * __uint_as_float(x.w << 16);
                B3.y += v * __uint_as_float(x.w & 0xffff0000u);
                rsb += v;
            }
        }
        // fold the 4 edge groups (lanes with equal sl share an m-slice)
#pragma unroll
        for (int ofs = 32; ofs >= 16; ofs >>= 1) {
            A0.x += __shfl_xor(A0.x, ofs); A0.y += __shfl_xor(A0.y, ofs);
            A1.x += __shfl_xor(A1.x, ofs); A1.y += __shfl_xor(A1.y, ofs);
            A2.x += __shfl_xor(A2.x, ofs); A2.y += __shfl_xor(A2.y, ofs);
            A3.x += __shfl_xor(A3.x, ofs); A3.y += __shfl_xor(A3.y, ofs);
            rsa  += __shfl_xor(rsa, ofs);
            B0.x += __shfl_xor(B0.x, ofs); B0.y += __shfl_xor(B0.y, ofs);
            B1.x += __shfl_xor(B1.x, ofs); B1.y += __shfl_xor(B1.y, ofs);
            B2.x += __shfl_xor(B2.x, ofs); B2.y += __shfl_xor(B2.y, ofs);
            B3.x += __shfl_xor(B3.x, ofs); B3.y += __shfl_xor(B3.y, ofs);
            rsb  += __shfl_xor(rsb, ofs);
        }
        {
            float inv = 1.0f / rsa;
            float2 w2 = (g == 0) ? A0 : (g == 1) ? A1 : (g == 2) ? A2 : A3;
            tile[sl * 8 + 2 * g][rl_a]     = w2.x * inv;
            tile[sl * 8 + 2 * g + 1][rl_a] = w2.y * inv;
        }
        if (has_b) {
            float inv = 1.0f / rsb;
            float2 w2 = (g == 0) ? B0 : (g == 1) ? B1 : (g == 2) ? B2 : B3;
            tile[sl * 8 + 2 * g][rl_a + 1]     = w2.x * inv;
            tile[sl * 8 + 2 * g + 1][rl_a + 1] = w2.y * inv;
        }
    }
    __syncthreads();

    // write phase: 16 groups x 32 lanes; group gw writes m = gw*8..gw*8+7
    int gw = tid >> 5;
    int l  = tid & 31;
    int r  = r0 + l;
    if (r < n) {
#pragma unroll
        for (int mi = 0; mi < 8; ++mi) {
            int m = gw * 8 + mi;
            size_t idx = (size_t)m * n + r;
            out[idx] = tile[m][l] + logits[idx];
        }
    }
}

// ============== fallback: round-9 CSR chain (smaller workspace) =============
__global__ void count_kernel(const int* __restrict__ rows,
                             int* __restrict__ counts, int nnz) {
    int e = (blockIdx.x * blockDim.x + threadIdx.x) * 4;
    if (e + 3 < nnz) {
        int4 r4 = *(const int4*)(rows + e);
        atomicAdd(&counts[r4.x], 1);
        atomicAdd(&counts[r4.y], 1);
        atomicAdd(&counts[r4.z], 1);
        atomicAdd(&counts[r4.w], 1);
    } else {
        for (int k = e; k < nnz; ++k) atomicAdd(&counts[rows[k]], 1);
    }
}

__global__ void scan1_kernel(const int* __restrict__ counts,
                             int* __restrict__ offsets,
                             int* __restrict__ blocksum, int n) {
    __shared__ int lds[1024];
    int tid = threadIdx.x;
    int gid = blockIdx.x * 1024 + tid;
    int v = (gid < n) ? counts[gid] : 0;
    lds[tid] = v;
    __syncthreads();
    for (int off = 1; off < 1024; off <<= 1) {
        int t = (tid >= off) ? lds[tid - off] : 0;
        __syncthreads();
        lds[tid] += t;
        __syncthreads();
    }
    if (gid < n) offsets[gid] = lds[tid] - v;
    if (tid == 1023) blocksum[blockIdx.x] = lds[1023];
}

__global__ void scan3_kernel(int* __restrict__ offsets,
                             int* __restrict__ cursor,
                             const int* __restrict__ blocksum, int n, int nb) {
    __shared__ int bsum[64];
    int tid = threadIdx.x;
    for (int i = tid; i < nb; i += 256) bsum[i] = blocksum[i];
    __syncthreads();
    int gid  = blockIdx.x * 256 + tid;
    int slab = (blockIdx.x * 256) >> 10;
    int carry = 0;
    for (int i = 0; i < slab; ++i) carry += bsum[i];
    if (gid < n) {
        int o = offsets[gid] + carry;
        offsets[gid] = o;
        cursor[gid]  = o;
    } else if (gid == n) {
        int total = 0;
        for (int i = 0; i < nb; ++i) total += bsum[i];
        offsets[n] = total;
    }
}

__global__ void scatter_kernel(const int* __restrict__ rows,
                               const int* __restrict__ cols,
                               const float* __restrict__ vals,
                               int* __restrict__ cursor,
                               uint2* __restrict__ epair, int nnz) {
    int e = blockIdx.x * blockDim.x + threadIdx.x;
    if (e < nnz) {
        int r = rows[e];
        int pos = atomicAdd(&cursor[r], 1);
        epair[pos] = make_uint2((unsigned)cols[e], __float_as_uint(vals[e]));
    }
}

__global__ void spmm_csr_kernel(const int* __restrict__ offsets,
                                const uint2* __restrict__ epair,
                                const unsigned short* __restrict__ flatTb,
                                const float* __restrict__ logits,
                                float* __restrict__ out, int n) {
    __shared__ float tile[128][33];
    const int tid  = threadIdx.x;
    const int wave = tid >> 6;
    const int lane = tid & 63;
    const int r0   = blockIdx.x * 32;
    for (int k = 0; k < 8; ++k) {
        int rl = wave * 8 + k;
        int r  = r0 + rl;
        if (r >= n) break;
        int start = __builtin_amdgcn_readfirstlane(offsets[r]);
        int end   = __builtin_amdgcn_readfirstlane(offsets[r + 1]);
        float2 a0 = {0.f, 0.f};
        float rsum = 0.f;
        for (int i = start; i < end; ++i) {
            uint2 ej = epair[i];
            float vj = __uint_as_float(ej.y);
            unsigned int xj = *((const unsigned int*)(flatTb + (size_t)ej.x * 128) + lane);
            a0.x += vj * __uint_as_float(xj << 16);
            a0.y += vj * __uint_as_float(xj & 0xffff0000u);
            rsum += vj;
        }
        float inv = 1.0f / rsum;
        tile[2 * lane][rl]     = a0.x * inv;
        tile[2 * lane + 1][rl] = a0.y * inv;
    }
    __syncthreads();
    int g = tid >> 5;
    int l = tid & 31;
    int r = r0 + l;
    if (r < n) {
#pragma unroll
        for (int mi = 0; mi < 16; ++mi) {
            int m = g * 16 + mi;
            size_t idx = (size_t)m * n + r;
            out[idx] = tile[m][l] + logits[idx];
        }
    }
}

extern "C" void kernel_launch(void* const* d_in, const int* in_sizes, int n_in,
                              void* d_out, int out_size, void* d_ws, size_t ws_size,
                              hipStream_t stream) {
    const float* logits = (const float*)d_in[0];
    const int*   adj    = (const int*)d_in[1];
    const float* vals   = (const float*)d_in[2];
    int nnz = in_sizes[2];
    int n   = NCLS;
    int m   = in_sizes[0] / n;     // 128
    const int* rows = adj;
    const int* cols = adj + nnz;
    float* out = (float*)d_out;

    size_t nm   = (size_t)n * m;
    int    nblk = (n + 31) / 32;
    // slotted layout: flatTb (nm*2) | epair (n*SLOT*8) | cnt (n*4)
    size_t slotted_bytes = nm * 2 + (size_t)n * SLOT * 8 + (size_t)n * 4 + 64;

    if (m == 128 && ws_size >= slotted_bytes) {
        unsigned short* flatTb = (unsigned short*)d_ws;
        uint2* epair = (uint2*)(flatTb + nm);
        int*   cnt   = (int*)(epair + (size_t)n * SLOT);

        dim3 tb(32, 8);
        dim3 tg(nblk, m / 32);
        transpose_in_kernel<<<tg, tb, 0, stream>>>(logits, flatTb, cnt, n, m);
        scatter_direct_kernel<<<(nnz / 4 + 255) / 256, 256, 0, stream>>>(rows, cols, vals,
                                                                         cnt, epair, nnz);
        spmm_fused_kernel<<<nblk, 512, 0, stream>>>(cnt, epair, flatTb, logits, out, n);
        return;
    }

    // -------- fallback: round-9 CSR chain --------
    int nb = (n + 1023) / 1024;
    unsigned short* flatTb = (unsigned short*)d_ws;
    uint2* epair    = (uint2*)(flatTb + nm);
    int*   counts   = (int*)(epair + nnz);
    int*   offs     = counts + n;
    int*   cursor   = offs + n + 1;
    int*   blocksum = cursor + n + 1;

    dim3 tb(32, 8);
    dim3 tg(nblk, m / 32);
    transpose_in_kernel<<<tg, tb, 0, stream>>>(logits, flatTb, counts, n, m);
    count_kernel<<<(nnz / 4 + 255) / 256, 256, 0, stream>>>(rows, counts, nnz);
    scan1_kernel<<<nb, 1024, 0, stream>>>(counts, offs, blocksum, n);
    scan3_kernel<<<(n + 1 + 255) / 256, 256, 0, stream>>>(offs, cursor,
                                                          blocksum, n, nb);
    scatter_kernel<<<(nnz + 255) / 256, 256, 0, stream>>>(rows, cols, vals,
                                                          cursor, epair, nnz);
    spmm_csr_kernel<<<nblk, 256, 0, stream>>>(offs, epair, flatTb, logits, out, n);
}

// Round 15
// 58.951 us; speedup vs baseline: 1.0135x; 1.0135x over previous
//
#include <hip/hip_runtime.h>

#define NCLS 30000
#define SLOT 64   // per-row edge-slot stride; P(deg>64) ~ 1e-24 for Poisson(16)

__device__ __forceinline__ unsigned short f2bf(float x) {
    unsigned int u = __float_as_uint(x);
    unsigned int r = (u + 0x7fffu + ((u >> 16) & 1u)) >> 16;   // RNE
    return (unsigned short)r;
}

// ---- transpose logits [M][N] -> flatTb [N][M] bf16; also zeroes cnt[n] ----
// 32n x 32m tile, 256 threads: ONE float4 load + ONE ushort4 store per thread.
__global__ void transpose_in_kernel(const float* __restrict__ src,
                                    unsigned short* __restrict__ dst,
                                    int* __restrict__ cnt, int n, int m) {
    __shared__ float tile[32][33];     // [m][n']
    int n0 = blockIdx.x * 32;
    int m0 = blockIdx.y * 32;
    int tx = threadIdx.x, ty = threadIdx.y;   // 8 x 32: tx=n-quad, ty=m
    if (blockIdx.y == 0) {
        int t = blockIdx.x * 256 + ty * 8 + tx;
        if (t < n) cnt[t] = 0;
    }
    // load: thread (tx,ty) reads src[m0+ty][n0+tx*4 .. +3]  (float4, coalesced)
    {
        int nn = n0 + tx * 4;
        float4 v = {0.f, 0.f, 0.f, 0.f};
        if (nn + 3 < n) {
            v = *(const float4*)(src + (size_t)(m0 + ty) * n + nn);
        } else {
            if (nn < n)     v.x = src[(size_t)(m0 + ty) * n + nn];
            if (nn + 1 < n) v.y = src[(size_t)(m0 + ty) * n + nn + 1];
            if (nn + 2 < n) v.z = src[(size_t)(m0 + ty) * n + nn + 2];
            if (nn + 3 < n) v.w = src[(size_t)(m0 + ty) * n + nn + 3];
        }
        tile[ty][tx * 4]     = v.x;
        tile[ty][tx * 4 + 1] = v.y;
        tile[ty][tx * 4 + 2] = v.z;
        tile[ty][tx * 4 + 3] = v.w;
    }
    __syncthreads();
    // store: thread handles n-row nn = n0 + (ty), m-quad mq = tx -> ushort4
    // remap: 256 threads = 32 n-rows x 8 m-quads
    {
        int nn = n0 + ty;          // 0..31
        int mq = tx;               // 0..7 -> m = m0 + mq*4 .. +3
        if (nn < n) {
            ushort4 o;
            o.x = f2bf(tile[mq * 4][ty]);
            o.y = f2bf(tile[mq * 4 + 1][ty]);
            o.z = f2bf(tile[mq * 4 + 2][ty]);
            o.w = f2bf(tile[mq * 4 + 3][ty]);
            *(ushort4*)(dst + (size_t)nn * m + m0 + mq * 4) = o;
        }
    }
}

// ---- direct slotted scatter, 4 edges/thread (int4 loads) ----
__global__ void scatter_direct_kernel(const int* __restrict__ rows,
                                      const int* __restrict__ cols,
                                      const float* __restrict__ vals,
                                      int* __restrict__ cnt,
                                      uint2* __restrict__ epair, int nnz) {
    int e = (blockIdx.x * blockDim.x + threadIdx.x) * 4;
    if (e + 3 < nnz) {
        int4  r4 = *(const int4*)(rows + e);
        int4  c4 = *(const int4*)(cols + e);
        float4 v4 = *(const float4*)(vals + e);
        int p0 = atomicAdd(&cnt[r4.x], 1) & (SLOT - 1);
        epair[(size_t)r4.x * SLOT + p0] = make_uint2((unsigned)c4.x, __float_as_uint(v4.x));
        int p1 = atomicAdd(&cnt[r4.y], 1) & (SLOT - 1);
        epair[(size_t)r4.y * SLOT + p1] = make_uint2((unsigned)c4.y, __float_as_uint(v4.y));
        int p2 = atomicAdd(&cnt[r4.z], 1) & (SLOT - 1);
        epair[(size_t)r4.z * SLOT + p2] = make_uint2((unsigned)c4.z, __float_as_uint(v4.z));
        int p3 = atomicAdd(&cnt[r4.w], 1) & (SLOT - 1);
        epair[(size_t)r4.w * SLOT + p3] = make_uint2((unsigned)c4.w, __float_as_uint(v4.w));
    } else {
        for (int k = e; k < nnz; ++k) {
            int r = rows[k];
            int pos = atomicAdd(&cnt[r], 1) & (SLOT - 1);
            epair[(size_t)r * SLOT + pos] =
                make_uint2((unsigned)cols[k], __float_as_uint(vals[k]));
        }
    }
}

// ---- fused SpMM + renormalize + transpose-out + residual ----
// block = 512 threads (8 waves); block owns 32 rows; wave w does rows w*4..w*4+3.
// Lane split: g = lane>>4 (edge sub-slot), sl = lane&15 (m = sl*8..sl*8+7);
// per chunk each lane gathers 16 B (uint4) -> one wave op covers 4 rows.
__global__ void __launch_bounds__(512)
spmm_fused_kernel(const int* __restrict__ cnt,
                  const uint2* __restrict__ epair,
                  const unsigned short* __restrict__ flatTb,
                  const float* __restrict__ logits,
                  float* __restrict__ out, int n) {
    __shared__ float tile[128][33];
    const int tid  = threadIdx.x;
    const int wave = tid >> 6;     // 0..7
    const int lane = tid & 63;
    const int g    = lane >> 4;    // edge slot within chunk: 0..3
    const int sl   = lane & 15;    // column slice: m = sl*8 .. sl*8+7
    const int r0   = blockIdx.x * 32;

    for (int k = 0; k < 4; ++k) {
        int rl = wave * 4 + k;
        int r  = r0 + rl;
        if (r >= n) break;
        int len = __builtin_amdgcn_readfirstlane(cnt[r]);
        if (len > SLOT) len = SLOT;
        int start = r * SLOT;
        int end   = start + len;

        float2 a0 = {0.f, 0.f}, a1 = {0.f, 0.f}, a2 = {0.f, 0.f}, a3 = {0.f, 0.f};
        float rsum = 0.f;

        for (int i = start; i < end; i += 4) {
            uint2 ed = epair[i + g];            // broadcast 8B: 4 addrs/wave
            bool act = (i + g) < end;
            unsigned c = act ? ed.x : 0u;       // poison-slot guard
            float    v = act ? __uint_as_float(ed.y) : 0.f;
            uint4 x = *((const uint4*)(flatTb + (size_t)c * 128) + sl);  // 16B
            a0.x += v * __uint_as_float(x.x << 16);
            a0.y += v * __uint_as_float(x.x & 0xffff0000u);
            a1.x += v * __uint_as_float(x.y << 16);
            a1.y += v * __uint_as_float(x.y & 0xffff0000u);
            a2.x += v * __uint_as_float(x.z << 16);
            a2.y += v * __uint_as_float(x.z & 0xffff0000u);
            a3.x += v * __uint_as_float(x.w << 16);
            a3.y += v * __uint_as_float(x.w & 0xffff0000u);
            rsum += v;
        }
        // fold the 4 edge groups (lanes with equal sl share an m-slice)
#pragma unroll
        for (int ofs = 32; ofs >= 16; ofs >>= 1) {
            a0.x += __shfl_xor(a0.x, ofs); a0.y += __shfl_xor(a0.y, ofs);
            a1.x += __shfl_xor(a1.x, ofs); a1.y += __shfl_xor(a1.y, ofs);
            a2.x += __shfl_xor(a2.x, ofs); a2.y += __shfl_xor(a2.y, ofs);
            a3.x += __shfl_xor(a3.x, ofs); a3.y += __shfl_xor(a3.y, ofs);
            rsum += __shfl_xor(rsum, ofs);
        }
        float inv = 1.0f / rsum;
        float2 w2 = (g == 0) ? a0 : (g == 1) ? a1 : (g == 2) ? a2 : a3;
        tile[sl * 8 + 2 * g][rl]     = w2.x * inv;
        tile[sl * 8 + 2 * g + 1][rl] = w2.y * inv;
    }
    __syncthreads();

    // write phase (vectorized): thread = (rq = t&7, mg = t>>3);
    // handles r = r0 + rq*4..+3 for m = mg*2, mg*2+1  -> float4 loads/stores
    {
        int rq = tid & 7;
        int mg = tid >> 3;           // 0..63 -> m rows mg*2, mg*2+1
        int rbase = r0 + rq * 4;
#pragma unroll
        for (int mi = 0; mi < 2; ++mi) {
            int m = mg * 2 + mi;
            size_t idx = (size_t)m * n + rbase;
            if (rbase + 3 < n) {
                float4 lg = *(const float4*)(logits + idx);
                float4 o;
                o.x = tile[m][rq * 4]     + lg.x;
                o.y = tile[m][rq * 4 + 1] + lg.y;
                o.z = tile[m][rq * 4 + 2] + lg.z;
                o.w = tile[m][rq * 4 + 3] + lg.w;
                *(float4*)(out + idx) = o;
            } else {
                for (int j = 0; j < 4; ++j) {
                    if (rbase + j < n)
                        out[idx + j] = tile[m][rq * 4 + j] + logits[idx + j];
                }
            }
        }
    }
}

// ============== fallback: round-9 CSR chain (smaller workspace) =============
__global__ void count_kernel(const int* __restrict__ rows,
                             int* __restrict__ counts, int nnz) {
    int e = (blockIdx.x * blockDim.x + threadIdx.x) * 4;
    if (e + 3 < nnz) {
        int4 r4 = *(const int4*)(rows + e);
        atomicAdd(&counts[r4.x], 1);
        atomicAdd(&counts[r4.y], 1);
        atomicAdd(&counts[r4.z], 1);
        atomicAdd(&counts[r4.w], 1);
    } else {
        for (int k = e; k < nnz; ++k) atomicAdd(&counts[rows[k]], 1);
    }
}

__global__ void scan1_kernel(const int* __restrict__ counts,
                             int* __restrict__ offsets,
                             int* __restrict__ blocksum, int n) {
    __shared__ int lds[1024];
    int tid = threadIdx.x;
    int gid = blockIdx.x * 1024 + tid;
    int v = (gid < n) ? counts[gid] : 0;
    lds[tid] = v;
    __syncthreads();
    for (int off = 1; off < 1024; off <<= 1) {
        int t = (tid >= off) ? lds[tid - off] : 0;
        __syncthreads();
        lds[tid] += t;
        __syncthreads();
    }
    if (gid < n) offsets[gid] = lds[tid] - v;
    if (tid == 1023) blocksum[blockIdx.x] = lds[1023];
}

__global__ void scan3_kernel(int* __restrict__ offsets,
                             int* __restrict__ cursor,
                             const int* __restrict__ blocksum, int n, int nb) {
    __shared__ int bsum[64];
    int tid = threadIdx.x;
    for (int i = tid; i < nb; i += 256) bsum[i] = blocksum[i];
    __syncthreads();
    int gid  = blockIdx.x * 256 + tid;
    int slab = (blockIdx.x * 256) >> 10;
    int carry = 0;
    for (int i = 0; i < slab; ++i) carry += bsum[i];
    if (gid < n) {
        int o = offsets[gid] + carry;
        offsets[gid] = o;
        cursor[gid]  = o;
    } else if (gid == n) {
        int total = 0;
        for (int i = 0; i < nb; ++i) total += bsum[i];
        offsets[n] = total;
    }
}

__global__ void scatter_kernel(const int* __restrict__ rows,
                               const int* __restrict__ cols,
                               const float* __restrict__ vals,
                               int* __restrict__ cursor,
                               uint2* __restrict__ epair, int nnz) {
    int e = blockIdx.x * blockDim.x + threadIdx.x;
    if (e < nnz) {
        int r = rows[e];
        int pos = atomicAdd(&cursor[r], 1);
        epair[pos] = make_uint2((unsigned)cols[e], __float_as_uint(vals[e]));
    }
}

__global__ void spmm_csr_kernel(const int* __restrict__ offsets,
                                const uint2* __restrict__ epair,
                                const unsigned short* __restrict__ flatTb,
                                const float* __restrict__ logits,
                                float* __restrict__ out, int n) {
    __shared__ float tile[128][33];
    const int tid  = threadIdx.x;
    const int wave = tid >> 6;
    const int lane = tid & 63;
    const int r0   = blockIdx.x * 32;
    for (int k = 0; k < 8; ++k) {
        int rl = wave * 8 + k;
        int r  = r0 + rl;
        if (r >= n) break;
        int start = __builtin_amdgcn_readfirstlane(offsets[r]);
        int end   = __builtin_amdgcn_readfirstlane(offsets[r + 1]);
        float2 a0 = {0.f, 0.f};
        float rsum = 0.f;
        for (int i = start; i < end; ++i) {
            uint2 ej = epair[i];
            float vj = __uint_as_float(ej.y);
            unsigned int xj = *((const unsigned int*)(flatTb + (size_t)ej.x * 128) + lane);
            a0.x += vj * __uint_as_float(xj << 16);
            a0.y += vj * __uint_as_float(xj & 0xffff0000u);
            rsum += vj;
        }
        float inv = 1.0f / rsum;
        tile[2 * lane][rl]     = a0.x * inv;
        tile[2 * lane + 1][rl] = a0.y * inv;
    }
    __syncthreads();
    int g = tid >> 5;
    int l = tid & 31;
    int r = r0 + l;
    if (r < n) {
#pragma unroll
        for (int mi = 0; mi < 16; ++mi) {
            int m = g * 16 + mi;
            size_t idx = (size_t)m * n + r;
            out[idx] = tile[m][l] + logits[idx];
        }
    }
}

extern "C" void kernel_launch(void* const* d_in, const int* in_sizes, int n_in,
                              void* d_out, int out_size, void* d_ws, size_t ws_size,
                              hipStream_t stream) {
    const float* logits = (const float*)d_in[0];
    const int*   adj    = (const int*)d_in[1];
    const float* vals   = (const float*)d_in[2];
    int nnz = in_sizes[2];
    int n   = NCLS;
    int m   = in_sizes[0] / n;     // 128
    const int* rows = adj;
    const int* cols = adj + nnz;
    float* out = (float*)d_out;

    size_t nm   = (size_t)n * m;
    int    nblk = (n + 31) / 32;
    // slotted layout: flatTb (nm*2) | epair (n*SLOT*8) | cnt (n*4)
    size_t slotted_bytes = nm * 2 + (size_t)n * SLOT * 8 + (size_t)n * 4 + 64;

    if (m == 128 && ws_size >= slotted_bytes) {
        unsigned short* flatTb = (unsigned short*)d_ws;
        uint2* epair = (uint2*)(flatTb + nm);
        int*   cnt   = (int*)(epair + (size_t)n * SLOT);

        dim3 tb(8, 32);
        dim3 tg(nblk, m / 32);
        transpose_in_kernel<<<tg, tb, 0, stream>>>(logits, flatTb, cnt, n, m);
        scatter_direct_kernel<<<(nnz / 4 + 255) / 256, 256, 0, stream>>>(rows, cols, vals,
                                                                         cnt, epair, nnz);
        spmm_fused_kernel<<<nblk, 512, 0, stream>>>(cnt, epair, flatTb, logits, out, n);
        return;
    }

    // -------- fallback: round-9 CSR chain --------
    int nb = (n + 1023) / 1024;
    unsigned short* flatTb = (unsigned short*)d_ws;
    uint2* epair    = (uint2*)(flatTb + nm);
    int*   counts   = (int*)(epair + nnz);
    int*   offs     = counts + n;
    int*   cursor   = offs + n + 1;
    int*   blocksum = cursor + n + 1;

    dim3 tb(8, 32);
    dim3 tg(nblk, m / 32);
    transpose_in_kernel<<<tg, tb, 0, stream>>>(logits, flatTb, counts, n, m);
    count_kernel<<<(nnz / 4 + 255) / 256, 256, 0, stream>>>(rows, counts, nnz);
    scan1_kernel<<<nb, 1024, 0, stream>>>(counts, offs, blocksum, n);
    scan3_kernel<<<(n + 1 + 255) / 256, 256, 0, stream>>>(offs, cursor,
                                                          blocksum, n, nb);
    scatter_kernel<<<(nnz + 255) / 256, 256, 0, stream>>>(rows, cols, vals,
                                                          cursor, epair, nnz);
    spmm_csr_kernel<<<nblk, 256, 0, stream>>>(offs, epair, flatTb, logits, out, n);
}